// Round 1
// baseline (174.980 us; speedup 1.0000x reference)
//
#include <hip/hip_runtime.h>
#include <hip/hip_bf16.h>

typedef __bf16 bf16_t;
typedef __bf16 bf16x8 __attribute__((ext_vector_type(8)));
typedef __bf16 bf16x4 __attribute__((ext_vector_type(4)));
typedef float  f32x4  __attribute__((ext_vector_type(4)));

#define SEQ    2048
#define BATCH  2
#define NHEAD  16
#define HDIM   64
#define DMODEL 1024
#define WIN    256

// async global->LDS, 16B per lane (dest = wave-uniform base + lane*16).
__device__ __forceinline__ void async_load16(const void* g, void* l) {
    __builtin_amdgcn_global_load_lds(
        (const __attribute__((address_space(1))) char*)(uintptr_t)g,
        (__attribute__((address_space(3))) char*)(uintptr_t)l, 16, 0, 0);
}

// ---------------------------------------------------------------------------
// Kernel 1: cast x (fp32) -> bf16, flat [4096][1024]
// ---------------------------------------------------------------------------
__global__ void cast_x_kernel(const float* __restrict__ x, bf16_t* __restrict__ xb, int n4) {
    int i = blockIdx.x * blockDim.x + threadIdx.x;
    if (i >= n4) return;
    float4 v = ((const float4*)x)[i];
    bf16x4 o;
    o[0] = (bf16_t)v.x; o[1] = (bf16_t)v.y; o[2] = (bf16_t)v.z; o[3] = (bf16_t)v.w;
    ((bf16x4*)xb)[i] = o;
}

// ---------------------------------------------------------------------------
// Kernel 2: transpose+cast weights into Wt[4][1024][1024] (B^T layout)
// ---------------------------------------------------------------------------
__global__ void transpose_w_kernel(const float* __restrict__ Wq, const float* __restrict__ Wk,
                                   const float* __restrict__ Wv, const float* __restrict__ Wo,
                                   bf16_t* __restrict__ Wt) {
    __shared__ float tile[32][33];
    const float* W = (blockIdx.z == 0) ? Wq : (blockIdx.z == 1) ? Wk : (blockIdx.z == 2) ? Wv : Wo;
    bf16_t* out = Wt + (size_t)blockIdx.z * DMODEL * DMODEL;
    int k0 = blockIdx.y * 32, n0 = blockIdx.x * 32;
    int tx = threadIdx.x, ty = threadIdx.y;  // block (32, 8)
#pragma unroll
    for (int i = 0; i < 4; i++)
        tile[ty + i * 8][tx] = W[(size_t)(k0 + ty + i * 8) * DMODEL + n0 + tx];
    __syncthreads();
#pragma unroll
    for (int i = 0; i < 4; i++)
        out[(size_t)(n0 + ty + i * 8) * DMODEL + k0 + tx] = (bf16_t)tile[tx][ty + i * 8];
}

// ---------------------------------------------------------------------------
// Kernel 3: V transpose, Vb[B,H,S,64] -> Vt[B,H,64,S]. Block (64,4), 64x64 tile.
// ---------------------------------------------------------------------------
__global__ __launch_bounds__(256) void vtrans_kernel(const bf16_t* __restrict__ Vb,
                                                     bf16_t* __restrict__ Vt) {
    __shared__ bf16_t tile[64][65];
    const int bh = blockIdx.y, s0 = blockIdx.x * 64;
    const int tx = threadIdx.x, ty = threadIdx.y;
    const bf16_t* src = Vb + ((size_t)bh * SEQ + s0) * HDIM;
    bf16_t* dst = Vt + (size_t)bh * HDIM * SEQ + s0;
#pragma unroll
    for (int i = 0; i < 16; i++) {
        int row = i * 4 + ty;
        tile[row][tx] = src[(size_t)row * HDIM + tx];      // coalesced 128B/wave
    }
    __syncthreads();
#pragma unroll
    for (int i = 0; i < 16; i++) {
        int d = i * 4 + ty;
        dst[(size_t)d * SEQ + tx] = tile[tx][d];           // coalesced 128B/wave
    }
}

// ---------------------------------------------------------------------------
// GEMM: C = A * Bt^T, 128x128 tile, swizzled global_load_lds staging,
// 1D grid with XCD-aware (n-strip per XCD) decomposition.
// EPI 0: QKV epilogue -> Qb(scaled by 1/sqrt(64)*log2(e))/Kb/Vb [B,H,S,64].
// EPI 1: Out = acc + bo (fp32).
// ---------------------------------------------------------------------------
template <int EPI>
__global__ __launch_bounds__(256) void gemm_bt_kernel(
    const bf16_t* __restrict__ A, const bf16_t* __restrict__ Bt,
    bf16_t* __restrict__ Qb, bf16_t* __restrict__ Kb, bf16_t* __restrict__ Vb,
    float* __restrict__ Out, const float* __restrict__ bo, int K, int nPer) {
    __shared__ __attribute__((aligned(16))) bf16_t As[128 * 64];
    __shared__ __attribute__((aligned(16))) bf16_t Bs[128 * 64];
    const int tid = threadIdx.x;
    const int wave = tid >> 6, lane = tid & 63, quad = lane >> 4, l15 = lane & 15;
    const int wm = wave >> 1, wn = wave & 1;
    // XCD swizzle: id&7 = XCD; each XCD owns an nPer-wide n-strip, m varies inside.
    const int id = blockIdx.x, xcd = id & 7, t = id >> 3;
    const int m0 = (t / nPer) * 128, n0 = (xcd * nPer + t % nPer) * 128;

    f32x4 acc[4][4] = {};

    for (int kt = 0; kt < K; kt += 64) {
#pragma unroll
        for (int i = 0; i < 4; i++) {
            int v = tid + i * 256;           // 1024 chunks of 16B per matrix
            int row = v >> 3, c = (v & 7) ^ (row & 7);
            async_load16(A + (size_t)(m0 + row) * K + kt + c * 8, (char*)As + (size_t)v * 16);
            async_load16(Bt + (size_t)(n0 + row) * K + kt + c * 8, (char*)Bs + (size_t)v * 16);
        }
        __syncthreads();
#pragma unroll
        for (int kk = 0; kk < 64; kk += 32) {
            bf16x8 am[4], bn[4];
#pragma unroll
            for (int i = 0; i < 4; i++) {
                int row = wm * 64 + i * 16 + l15;
                int ch = ((kk >> 3) + quad) ^ (row & 7);
                am[i] = *(const bf16x8*)&As[row * 64 + ch * 8];
            }
#pragma unroll
            for (int j = 0; j < 4; j++) {
                int row = wn * 64 + j * 16 + l15;
                int ch = ((kk >> 3) + quad) ^ (row & 7);
                bn[j] = *(const bf16x8*)&Bs[row * 64 + ch * 8];
            }
#pragma unroll
            for (int i = 0; i < 4; i++)
#pragma unroll
                for (int j = 0; j < 4; j++)
                    acc[i][j] = __builtin_amdgcn_mfma_f32_16x16x32_bf16(am[i], bn[j], acc[i][j], 0, 0, 0);
        }
        __syncthreads();
    }

#pragma unroll
    for (int i = 0; i < 4; i++)
#pragma unroll
        for (int j = 0; j < 4; j++)
#pragma unroll
            for (int r = 0; r < 4; r++) {
                int mg = m0 + wm * 64 + i * 16 + quad * 4 + r;
                int ng = n0 + wn * 64 + j * 16 + l15;
                float v = acc[i][j][r];
                if (EPI == 0) {
                    int sel = ng >> 10, nl = ng & 1023, h = nl >> 6, d = nl & 63;
                    int b = mg >> 11, s = mg & 2047;
                    size_t idx = ((size_t)((b * NHEAD + h) * SEQ) + s) * HDIM + d;
                    // 0.125 = 1/sqrt(64); *log2(e) so attention can use exp2.
                    if (sel == 0)      Qb[idx] = (bf16_t)(v * 0.18033688011112042f);
                    else if (sel == 1) Kb[idx] = (bf16_t)v;
                    else               Vb[idx] = (bf16_t)v;
                } else {
                    Out[(size_t)mg * DMODEL + ng] = v + bo[ng];
                }
            }
}

// ---------------------------------------------------------------------------
// Attention v5: 512 threads, 2 query-tiles (128 queries) per block; waves 0-3
// own qtile A rows, waves 4-7 qtile A+1. Block stages the union window (10
// K/V tiles), each wave computes only its own 9 in-window tiles.
//
// v5 changes vs v4:
//  - QK^T computed SWAPPED: st = mfma(kb, qa). For 16x16x32 the A-fragment
//    (row=l15, k=quad*8+j) and B-fragment (col=l15, k=quad*8+j) are per-lane
//    identical data, so the same registers serve either operand slot. The
//    S^T output layout puts a lane's 4 acc regs at 4 CONSECUTIVE k for one
//    q=l15 -> P tile stores become 4x ds_write_b64 instead of 16x ds_write_u16.
//  - exp2f with log2(e) pre-folded into the Q scale (no per-element mul).
//  - single __syncthreads per k-tile (top-of-loop barrier orders both the
//    staging completion and the double-buffer reuse).
// ---------------------------------------------------------------------------
__global__ __launch_bounds__(512) void attn_kernel(
    const bf16_t* __restrict__ Qb, const bf16_t* __restrict__ Kb,
    const bf16_t* __restrict__ Vt, bf16_t* __restrict__ ctx) {
    __shared__ __attribute__((aligned(16))) bf16_t Ks[2][64 * 64];
    __shared__ __attribute__((aligned(16))) bf16_t Vs[2][64 * 64];
    __shared__ __attribute__((aligned(16))) bf16_t Plds[8][16][72];
    const int tid = threadIdx.x;
    const int wave = tid >> 6, lane = tid & 63, quad = lane >> 4, l15 = lane & 15;

    // 512 blocks; XCD gets 64 consecutive tasks = 4 heads x 16 query-pairs.
    const int id = blockIdx.x;
    const int task = (id & 7) * 64 + (id >> 3);
    const int b = task >> 8, h = (task >> 4) & 15, Q0 = (task & 15) << 7;
    const int qbase = Q0 + wave * 16;
    const int wqt = (Q0 >> 6) + (wave >> 2);   // this wave's 64-aligned q-tile

    const bf16_t* Qp = Qb + (size_t)(b * NHEAD + h) * SEQ * HDIM;
    const bf16_t* Kp = Kb + (size_t)(b * NHEAD + h) * SEQ * HDIM;
    const bf16_t* Vp = Vt + (size_t)(b * NHEAD + h) * HDIM * SEQ;

    bf16x8 qa0 = *(const bf16x8*)(Qp + (size_t)(qbase + l15) * HDIM + quad * 8);
    bf16x8 qa1 = *(const bf16x8*)(Qp + (size_t)(qbase + l15) * HDIM + 32 + quad * 8);

    bf16x8 ones;
#pragma unroll
    for (int j = 0; j < 8; j++) ones[j] = (bf16_t)1.0f;

    f32x4 O[4] = {};
    f32x4 lacc = {};

    const int base_t = Q0 >> 6;
    const int bt0 = (base_t - 4 > 0) ? base_t - 4 : 0;
    const int bt1 = (base_t + 5 < SEQ / 64 - 1) ? base_t + 5 : SEQ / 64 - 1;

    auto stage = [&](int kt, int buf) {
        const int k0 = kt * 64;
        int v = tid;                          // 512 chunks of 16B each
        int row = v >> 3, c = (v & 7) ^ (row & 7);
        async_load16(Kp + (size_t)(k0 + row) * HDIM + c * 8, (char*)&Ks[buf][0] + (size_t)v * 16);
        async_load16(Vp + (size_t)row * SEQ + k0 + c * 8, (char*)&Vs[buf][0] + (size_t)v * 16);
    };

    stage(bt0, 0);
    int cb = 0;
    for (int kt = bt0; kt <= bt1; kt++) {
        // One barrier per tile: (a) the wave's own vmcnt(0) drain before
        // s_barrier makes stage(kt -> cb) visible to all, (b) it also
        // guarantees everyone is done reading cb^1 (read during iter kt-1)
        // before stage(kt+1) overwrites it.
        __syncthreads();
        if (kt < bt1) stage(kt + 1, cb ^ 1);
        const int dt = kt - wqt;
        if (dt >= -4 && dt <= 4) {             // wave-uniform window check
            const int k0 = kt * 64;
            f32x4 st[4];
#pragma unroll
            for (int c = 0; c < 4; c++) {
                int row = c * 16 + l15;
                bf16x8 kb0 = *(const bf16x8*)&Ks[cb][row * 64 + (quad ^ (row & 7)) * 8];
                bf16x8 kb1 = *(const bf16x8*)&Ks[cb][row * 64 + ((quad + 4) ^ (row & 7)) * 8];
                f32x4 a = {};
                a = __builtin_amdgcn_mfma_f32_16x16x32_bf16(kb0, qa0, a, 0, 0, 0);  // S^T
                a = __builtin_amdgcn_mfma_f32_16x16x32_bf16(kb1, qa1, a, 0, 0, 0);
                st[c] = a;
            }
            const bool edge = (dt == -4 || dt == 4);
            const int q = qbase + l15;
#pragma unroll
            for (int c = 0; c < 4; c++) {
                bf16x4 pk;
#pragma unroll
                for (int r = 0; r < 4; r++) {
                    float sv = st[c][r];
                    if (edge) {
                        int k = k0 + c * 16 + quad * 4 + r;
                        int dd = q - k; dd = (dd < 0) ? -dd : dd;
                        if (dd > WIN) sv = -1e30f;
                    }
                    pk[r] = (bf16_t)exp2f(sv);
                }
                *(bf16x4*)&Plds[wave][l15][c * 16 + quad * 4] = pk;   // ds_write_b64
            }
            bf16x8 pa0 = *(const bf16x8*)&Plds[wave][l15][quad * 8];
            bf16x8 pa1 = *(const bf16x8*)&Plds[wave][l15][32 + quad * 8];
            lacc = __builtin_amdgcn_mfma_f32_16x16x32_bf16(pa0, ones, lacc, 0, 0, 0);
            lacc = __builtin_amdgcn_mfma_f32_16x16x32_bf16(pa1, ones, lacc, 0, 0, 0);
#pragma unroll
            for (int d = 0; d < 4; d++) {
                int row = d * 16 + l15;
                bf16x8 vb0 = *(const bf16x8*)&Vs[cb][row * 64 + (quad ^ (row & 7)) * 8];
                bf16x8 vb1 = *(const bf16x8*)&Vs[cb][row * 64 + ((quad + 4) ^ (row & 7)) * 8];
                O[d] = __builtin_amdgcn_mfma_f32_16x16x32_bf16(pa0, vb0, O[d], 0, 0, 0);
                O[d] = __builtin_amdgcn_mfma_f32_16x16x32_bf16(pa1, vb1, O[d], 0, 0, 0);
            }
        }
        cb ^= 1;
    }

#pragma unroll
    for (int r = 0; r < 4; r++) {
        float inv = 1.0f / lacc[r];
        int i = qbase + quad * 4 + r;
#pragma unroll
        for (int d = 0; d < 4; d++) {
            float v = O[d][r] * inv;
            ctx[((size_t)(b * SEQ + i)) * DMODEL + h * HDIM + d * 16 + l15] = (bf16_t)v;
        }
    }
}

// ---------------------------------------------------------------------------
extern "C" void kernel_launch(void* const* d_in, const int* in_sizes, int n_in,
                              void* d_out, int out_size, void* d_ws, size_t ws_size,
                              hipStream_t stream) {
    const float* x  = (const float*)d_in[0];
    const float* Wq = (const float*)d_in[1];
    const float* Wk = (const float*)d_in[2];
    const float* Wv = (const float*)d_in[3];
    const float* Wo = (const float*)d_in[4];
    const float* bo = (const float*)d_in[5];
    float* out = (float*)d_out;

    const size_t MTOK = (size_t)BATCH * SEQ;          // 4096
    bf16_t* xb  = (bf16_t*)d_ws;                      // 4096*1024
    bf16_t* Wt  = xb + MTOK * DMODEL;                 // 4*1024*1024
    bf16_t* Qb  = Wt + (size_t)4 * DMODEL * DMODEL;   // [B,H,S,64]
    bf16_t* Kb  = Qb + MTOK * DMODEL;                 // [B,H,S,64]
    bf16_t* Vt  = Kb + MTOK * DMODEL;                 // [B,H,64,S]
    bf16_t* ctx = Vt + MTOK * DMODEL;                 // [4096][1024]
    bf16_t* Vb  = ctx;  // alias: Vb dead before attn writes ctx

    cast_x_kernel<<<dim3((MTOK * DMODEL / 4 + 255) / 256), dim3(256), 0, stream>>>(
        x, xb, (int)(MTOK * DMODEL / 4));
    transpose_w_kernel<<<dim3(32, 32, 4), dim3(32, 8), 0, stream>>>(Wq, Wk, Wv, Wo, Wt);
    // QKV: M=4096, N=3072, K=1024; 768 blocks, 3 n-strips per XCD
    gemm_bt_kernel<0><<<dim3(768), dim3(256), 0, stream>>>(
        xb, Wt, Qb, Kb, Vb, nullptr, nullptr, DMODEL, 3);
    vtrans_kernel<<<dim3(32, 32), dim3(64, 4), 0, stream>>>(Vb, Vt);
    attn_kernel<<<dim3(512), dim3(512), 0, stream>>>(Qb, Kb, Vt, ctx);
    // Out: M=4096, N=1024, K=1024; 256 blocks, 1 n-strip per XCD
    gemm_bt_kernel<1><<<dim3(256), dim3(256), 0, stream>>>(
        ctx, Wt + (size_t)3 * DMODEL * DMODEL, nullptr, nullptr, nullptr, out, bo, DMODEL, 1);
}

// Round 3
// 167.617 us; speedup vs baseline: 1.0439x; 1.0439x over previous
//
#include <hip/hip_runtime.h>
#include <hip/hip_bf16.h>

typedef __bf16 bf16_t;
typedef __bf16 bf16x8 __attribute__((ext_vector_type(8)));
typedef __bf16 bf16x4 __attribute__((ext_vector_type(4)));
typedef float  f32x4  __attribute__((ext_vector_type(4)));

#define SEQ    2048
#define BATCH  2
#define NHEAD  16
#define HDIM   64
#define DMODEL 1024
#define WIN    256

// async global->LDS, 16B per lane (dest = wave-uniform base + lane*16).
__device__ __forceinline__ void async_load16(const void* g, void* l) {
    __builtin_amdgcn_global_load_lds(
        (const __attribute__((address_space(1))) char*)(uintptr_t)g,
        (__attribute__((address_space(3))) char*)(uintptr_t)l, 16, 0, 0);
}

// ---------------------------------------------------------------------------
// Prep kernel: blocks 0..1023 transpose+cast the 4 weight mats (64x64 tiles,
// float4 reads); blocks 1024..2047 cast x -> bf16 (float4).
// ---------------------------------------------------------------------------
__global__ __launch_bounds__(256) void prep_kernel(
    const float* __restrict__ x, const float* __restrict__ Wq,
    const float* __restrict__ Wk, const float* __restrict__ Wv,
    const float* __restrict__ Wo, bf16_t* __restrict__ xb,
    bf16_t* __restrict__ Wt) {
    const int bid = blockIdx.x, tid = threadIdx.x;
    if (bid < 1024) {
        __shared__ float t64[64][65];
        const int mat = bid >> 8, tile = bid & 255;
        const int k0 = (tile >> 4) * 64, n0 = (tile & 15) * 64;
        const float* W = (mat == 0) ? Wq : (mat == 1) ? Wk : (mat == 2) ? Wv : Wo;
        bf16_t* out = Wt + (size_t)mat * DMODEL * DMODEL;
        const int r = tid >> 4, c4 = tid & 15;
#pragma unroll
        for (int i = 0; i < 4; i++) {
            int krow = i * 16 + r;
            float4 v = *(const float4*)&W[(size_t)(k0 + krow) * DMODEL + n0 + c4 * 4];
            t64[krow][c4 * 4 + 0] = v.x; t64[krow][c4 * 4 + 1] = v.y;
            t64[krow][c4 * 4 + 2] = v.z; t64[krow][c4 * 4 + 3] = v.w;
        }
        __syncthreads();
#pragma unroll
        for (int j = 0; j < 4; j++) {
            int nrow = j * 16 + r;
            bf16x4 o;
#pragma unroll
            for (int q = 0; q < 4; q++) o[q] = (bf16_t)t64[c4 * 4 + q][nrow];
            *(bf16x4*)&out[(size_t)(n0 + nrow) * DMODEL + k0 + c4 * 4] = o;
        }
    } else {
        const int cb = bid - 1024;
#pragma unroll
        for (int it = 0; it < 4; it++) {
            int i = (cb * 4 + it) * 256 + tid;
            float4 v = ((const float4*)x)[i];
            bf16x4 o;
            o[0] = (bf16_t)v.x; o[1] = (bf16_t)v.y; o[2] = (bf16_t)v.z; o[3] = (bf16_t)v.w;
            ((bf16x4*)xb)[i] = o;
        }
    }
}

// ---------------------------------------------------------------------------
// QKV GEMM: 256x256 tile, BK=64, 8 waves (2M x 4N), 4-phase schedule.
// RACE-SAFE REDESIGN: every global_load_lds issued during iter t targets
// buffer cur^1 ONLY (tile t+1) -- no write can ever touch the buffer being
// read this iteration, regardless of compiler instruction motion.
// Groups (per-thread 16B loads): gr0..3 = A rows 0..63/64..127/128..191/
// 192..255; gr4..7 = B same. P0 reads need gr0,gr2,gr4..7; P2 (A-high)
// reads need gr1,gr3.
// Issue order per iter: P0->gr4,5  P1->gr6,7  P2->gr0,2  P3->gr1,3.
// Waits: P1-end vmcnt(4) (drains gr1,gr3 of t before P2 A-high reads;
// barrier after for cross-wave visibility); boundary vmcnt(2) (leaves
// gr1,gr3 of t+1 in flight -- counted, never 0 in steady state).
// ---------------------------------------------------------------------------
__global__ __launch_bounds__(512, 2) void gemm_qkv_kernel(
    const bf16_t* __restrict__ A, const bf16_t* __restrict__ Bt,
    bf16_t* __restrict__ Qb, bf16_t* __restrict__ Kb, bf16_t* __restrict__ Vb) {
    __shared__ __attribute__((aligned(16))) bf16_t smem[2][2][256 * 64];
    const int tid = threadIdx.x;
    const int wave = tid >> 6, lane = tid & 63, quad = lane >> 4, l15 = lane & 15;
    const int wm = wave >> 2, wn = wave & 3;
    const int id = blockIdx.x, xcd = id & 7, tt = id >> 3;
    const int gidx = xcd * 24 + tt;                 // 192 blocks, bijective
    const int m0 = (gidx & 15) * 256, n0 = (gidx >> 4) * 256;

    const int cth = (tid & 7) ^ ((tid >> 3) & 7);   // swizzled source chunk
    const int rA = tid >> 3;                        // row-in-group 0..63

    auto stageG = [&](int tile, int gr, int buf) {
        const int row = (gr & 3) * 64 + rA;
        const bf16_t* src = (gr < 4)
            ? A  + (size_t)(m0 + row) * 1024 + tile * 64 + cth * 8
            : Bt + (size_t)(n0 + row) * 1024 + tile * 64 + cth * 8;
        async_load16(src, (char*)&smem[buf][gr >> 2][0] + (size_t)((gr & 3) * 512 + tid) * 16);
    };

    const int swz  = l15 & 7;
    const int chk0 = (quad ^ swz) * 8;              // kk=0 phys chunk offset
    const int chk1 = ((4 + quad) ^ swz) * 8;        // kk=32
    const int rowA = wm * 128 + l15;
    const int rowB = wn * 64 + l15;

    f32x4 acc[8][4] = {};

    // Prologue = steady-state issue order for tile 0; invariant at loop top:
    // outstanding (own wave) == [gr1,gr3 of tile t].
    stageG(0, 4, 0); stageG(0, 5, 0); stageG(0, 6, 0); stageG(0, 7, 0);
    stageG(0, 0, 0); stageG(0, 2, 0); stageG(0, 1, 0); stageG(0, 3, 0);
    asm volatile("s_waitcnt vmcnt(2)" ::: "memory");
    __builtin_amdgcn_s_barrier();
    __builtin_amdgcn_sched_barrier(0);

    int cur = 0;
#pragma unroll 1
    for (int t = 0; t < 16; ++t) {
        const bf16_t* as = &smem[cur][0][0];
        const bf16_t* bs = &smem[cur][1][0];
        bf16x8 am0[4], am1[4], ba0[2], ba1[2], bb0[2], bb1[2];
        // ---- P0: read A-low + B-low; issue gr4,gr5(t+1) -> cur^1
#pragma unroll
        for (int i = 0; i < 4; i++) {
            am0[i] = *(const bf16x8*)&as[(rowA + i * 16) * 64 + chk0];
            am1[i] = *(const bf16x8*)&as[(rowA + i * 16) * 64 + chk1];
        }
#pragma unroll
        for (int j = 0; j < 2; j++) {
            ba0[j] = *(const bf16x8*)&bs[(rowB + j * 16) * 64 + chk0];
            ba1[j] = *(const bf16x8*)&bs[(rowB + j * 16) * 64 + chk1];
        }
        if (t + 1 < 16) { stageG(t + 1, 4, cur ^ 1); stageG(t + 1, 5, cur ^ 1); }
        __builtin_amdgcn_s_barrier();
        __builtin_amdgcn_sched_barrier(0);
        __builtin_amdgcn_s_setprio(1);
#pragma unroll
        for (int i = 0; i < 4; i++)
#pragma unroll
            for (int j = 0; j < 2; j++) {
                acc[i][j] = __builtin_amdgcn_mfma_f32_16x16x32_bf16(am0[i], ba0[j], acc[i][j], 0, 0, 0);
                acc[i][j] = __builtin_amdgcn_mfma_f32_16x16x32_bf16(am1[i], ba1[j], acc[i][j], 0, 0, 0);
            }
        __builtin_amdgcn_s_setprio(0);
        __builtin_amdgcn_s_barrier();
        __builtin_amdgcn_sched_barrier(0);
        // ---- P1: read B-high; issue gr6,gr7(t+1) -> cur^1
#pragma unroll
        for (int j = 0; j < 2; j++) {
            bb0[j] = *(const bf16x8*)&bs[(rowB + (j + 2) * 16) * 64 + chk0];
            bb1[j] = *(const bf16x8*)&bs[(rowB + (j + 2) * 16) * 64 + chk1];
        }
        if (t + 1 < 16) { stageG(t + 1, 6, cur ^ 1); stageG(t + 1, 7, cur ^ 1); }
        __builtin_amdgcn_s_barrier();
        __builtin_amdgcn_sched_barrier(0);
        __builtin_amdgcn_s_setprio(1);
#pragma unroll
        for (int i = 0; i < 4; i++)
#pragma unroll
            for (int j = 0; j < 2; j++) {
                acc[i][j + 2] = __builtin_amdgcn_mfma_f32_16x16x32_bf16(am0[i], bb0[j], acc[i][j + 2], 0, 0, 0);
                acc[i][j + 2] = __builtin_amdgcn_mfma_f32_16x16x32_bf16(am1[i], bb1[j], acc[i][j + 2], 0, 0, 0);
            }
        __builtin_amdgcn_s_setprio(0);
        // drain gr1,gr3(t) before P2's A-high reads (others' portions become
        // visible via the barrier that follows).
        if (t + 1 < 16) asm volatile("s_waitcnt vmcnt(4)" ::: "memory");
        else            asm volatile("s_waitcnt vmcnt(0)" ::: "memory");
        __builtin_amdgcn_s_barrier();
        __builtin_amdgcn_sched_barrier(0);
        // ---- P2: read A-high (reuse am regs); issue gr0,gr2(t+1) -> cur^1
#pragma unroll
        for (int i = 0; i < 4; i++) {
            am0[i] = *(const bf16x8*)&as[(rowA + (i + 4) * 16) * 64 + chk0];
            am1[i] = *(const bf16x8*)&as[(rowA + (i + 4) * 16) * 64 + chk1];
        }
        if (t + 1 < 16) { stageG(t + 1, 0, cur ^ 1); stageG(t + 1, 2, cur ^ 1); }
        __builtin_amdgcn_s_barrier();
        __builtin_amdgcn_sched_barrier(0);
        __builtin_amdgcn_s_setprio(1);
#pragma unroll
        for (int i = 0; i < 4; i++)
#pragma unroll
            for (int j = 0; j < 2; j++) {
                acc[i + 4][j + 2] = __builtin_amdgcn_mfma_f32_16x16x32_bf16(am0[i], bb0[j], acc[i + 4][j + 2], 0, 0, 0);
                acc[i + 4][j + 2] = __builtin_amdgcn_mfma_f32_16x16x32_bf16(am1[i], bb1[j], acc[i + 4][j + 2], 0, 0, 0);
            }
        __builtin_amdgcn_s_setprio(0);
        __builtin_amdgcn_s_barrier();
        __builtin_amdgcn_sched_barrier(0);
        // ---- P3: issue gr1,gr3(t+1) -> cur^1; A-high x B-low (regs only)
        if (t + 1 < 16) { stageG(t + 1, 1, cur ^ 1); stageG(t + 1, 3, cur ^ 1); }
        __builtin_amdgcn_s_setprio(1);
#pragma unroll
        for (int i = 0; i < 4; i++)
#pragma unroll
            for (int j = 0; j < 2; j++) {
                acc[i + 4][j] = __builtin_amdgcn_mfma_f32_16x16x32_bf16(am0[i], ba0[j], acc[i + 4][j], 0, 0, 0);
                acc[i + 4][j] = __builtin_amdgcn_mfma_f32_16x16x32_bf16(am1[i], ba1[j], acc[i + 4][j], 0, 0, 0);
            }
        __builtin_amdgcn_s_setprio(0);
        // boundary: drain through gr0,gr2(t+1); leave gr1,gr3(t+1) in flight.
        if (t + 1 < 16) {
            asm volatile("s_waitcnt vmcnt(2)" ::: "memory");
            __builtin_amdgcn_s_barrier();
            __builtin_amdgcn_sched_barrier(0);
        }
        cur ^= 1;
    }

#pragma unroll
    for (int i = 0; i < 8; i++)
#pragma unroll
        for (int j = 0; j < 4; j++)
#pragma unroll
            for (int r = 0; r < 4; r++) {
                int mg = m0 + wm * 128 + i * 16 + quad * 4 + r;
                int ng = n0 + wn * 64 + j * 16 + l15;
                float v = acc[i][j][r];
                int sel = ng >> 10, nl = ng & 1023, h = nl >> 6, d = nl & 63;
                int b = mg >> 11, s = mg & 2047;
                size_t idx = ((size_t)((b * NHEAD + h) * SEQ) + s) * HDIM + d;
                if (sel == 0)      Qb[idx] = (bf16_t)(v * 0.18033688011112042f);
                else if (sel == 1) Kb[idx] = (bf16_t)v;
                else               Vb[idx] = (bf16_t)v;
            }
}

// ---------------------------------------------------------------------------
// Out GEMM: 128x128 tile, 2-phase double-buffer with __syncthreads drains
// (provably safe: sync implies vmcnt(0)+lgkmcnt(0)+barrier).
// ---------------------------------------------------------------------------
__global__ __launch_bounds__(256) void gemm_out_kernel(
    const bf16_t* __restrict__ A, const bf16_t* __restrict__ Bt,
    float* __restrict__ Out, const float* __restrict__ bo) {
    __shared__ __attribute__((aligned(16))) bf16_t As[2][128 * 64];
    __shared__ __attribute__((aligned(16))) bf16_t Bs[2][128 * 64];
    const int tid = threadIdx.x;
    const int wave = tid >> 6, lane = tid & 63, quad = lane >> 4, l15 = lane & 15;
    const int wm = wave >> 1, wn = wave & 1;
    const int id = blockIdx.x, xcd = id & 7, t = id >> 3;
    const int m0 = t * 128, n0 = xcd * 128;        // M=4096 x N=1024

    auto stage = [&](int kt, int buf) {
#pragma unroll
        for (int i = 0; i < 4; i++) {
            int v = tid + i * 256;
            int row = v >> 3, c = (v & 7) ^ (row & 7);
            async_load16(A + (size_t)(m0 + row) * 1024 + kt * 64 + c * 8,
                         (char*)&As[buf][0] + (size_t)v * 16);
            async_load16(Bt + (size_t)(n0 + row) * 1024 + kt * 64 + c * 8,
                         (char*)&Bs[buf][0] + (size_t)v * 16);
        }
    };

    f32x4 acc[4][4] = {};
    stage(0, 0);
    __syncthreads();
    int cur = 0;
    for (int kt = 0; kt < 16; ++kt) {
        if (kt + 1 < 16) stage(kt + 1, cur ^ 1);
#pragma unroll
        for (int kk = 0; kk < 64; kk += 32) {
            bf16x8 am[4], bn[4];
#pragma unroll
            for (int i = 0; i < 4; i++) {
                int row = wm * 64 + i * 16 + l15;
                int ch = ((kk >> 3) + quad) ^ (row & 7);
                am[i] = *(const bf16x8*)&As[cur][row * 64 + ch * 8];
            }
#pragma unroll
            for (int j = 0; j < 4; j++) {
                int row = wn * 64 + j * 16 + l15;
                int ch = ((kk >> 3) + quad) ^ (row & 7);
                bn[j] = *(const bf16x8*)&Bs[cur][row * 64 + ch * 8];
            }
#pragma unroll
            for (int i = 0; i < 4; i++)
#pragma unroll
                for (int j = 0; j < 4; j++)
                    acc[i][j] = __builtin_amdgcn_mfma_f32_16x16x32_bf16(am[i], bn[j], acc[i][j], 0, 0, 0);
        }
        __syncthreads();                           // vmcnt(0)+barrier drain
        cur ^= 1;
    }

#pragma unroll
    for (int i = 0; i < 4; i++)
#pragma unroll
        for (int j = 0; j < 4; j++)
#pragma unroll
            for (int r = 0; r < 4; r++) {
                int mg = m0 + wm * 64 + i * 16 + quad * 4 + r;
                int ng = n0 + wn * 64 + j * 16 + l15;
                Out[(size_t)mg * DMODEL + ng] = acc[i][j][r] + bo[ng];
            }
}

// ---------------------------------------------------------------------------
// Kernel: V transpose, Vb[B,H,S,64] -> Vt[B,H,64,S]. Block (64,4), 64x64 tile.
// ---------------------------------------------------------------------------
__global__ __launch_bounds__(256) void vtrans_kernel(const bf16_t* __restrict__ Vb,
                                                     bf16_t* __restrict__ Vt) {
    __shared__ bf16_t tile[64][65];
    const int bh = blockIdx.y, s0 = blockIdx.x * 64;
    const int tx = threadIdx.x, ty = threadIdx.y;
    const bf16_t* src = Vb + ((size_t)bh * SEQ + s0) * HDIM;
    bf16_t* dst = Vt + (size_t)bh * HDIM * SEQ + s0;
#pragma unroll
    for (int i = 0; i < 16; i++) {
        int row = i * 4 + ty;
        tile[row][tx] = src[(size_t)row * HDIM + tx];
    }
    __syncthreads();
#pragma unroll
    for (int i = 0; i < 16; i++) {
        int d = i * 4 + ty;
        dst[(size_t)d * SEQ + tx] = tile[tx][d];
    }
}

// ---------------------------------------------------------------------------
// Attention v5 (proven in rounds 0-1): swapped QK^T, exp2, 1 __syncthreads
// per tile (safe: sync = vmcnt(0)+lgkmcnt(0)+barrier).
// ---------------------------------------------------------------------------
__global__ __launch_bounds__(512) void attn_kernel(
    const bf16_t* __restrict__ Qb, const bf16_t* __restrict__ Kb,
    const bf16_t* __restrict__ Vt, bf16_t* __restrict__ ctx) {
    __shared__ __attribute__((aligned(16))) bf16_t Ks[2][64 * 64];
    __shared__ __attribute__((aligned(16))) bf16_t Vs[2][64 * 64];
    __shared__ __attribute__((aligned(16))) bf16_t Plds[8][16][72];
    const int tid = threadIdx.x;
    const int wave = tid >> 6, lane = tid & 63, quad = lane >> 4, l15 = lane & 15;

    const int id = blockIdx.x;
    const int task = (id & 7) * 64 + (id >> 3);
    const int b = task >> 8, h = (task >> 4) & 15, Q0 = (task & 15) << 7;
    const int qbase = Q0 + wave * 16;
    const int wqt = (Q0 >> 6) + (wave >> 2);

    const bf16_t* Qp = Qb + (size_t)(b * NHEAD + h) * SEQ * HDIM;
    const bf16_t* Kp = Kb + (size_t)(b * NHEAD + h) * SEQ * HDIM;
    const bf16_t* Vp = Vt + (size_t)(b * NHEAD + h) * HDIM * SEQ;

    bf16x8 qa0 = *(const bf16x8*)(Qp + (size_t)(qbase + l15) * HDIM + quad * 8);
    bf16x8 qa1 = *(const bf16x8*)(Qp + (size_t)(qbase + l15) * HDIM + 32 + quad * 8);

    bf16x8 ones;
#pragma unroll
    for (int j = 0; j < 8; j++) ones[j] = (bf16_t)1.0f;

    f32x4 O[4] = {};
    f32x4 lacc = {};

    const int base_t = Q0 >> 6;
    const int bt0 = (base_t - 4 > 0) ? base_t - 4 : 0;
    const int bt1 = (base_t + 5 < SEQ / 64 - 1) ? base_t + 5 : SEQ / 64 - 1;

    auto stage = [&](int kt, int buf) {
        const int k0 = kt * 64;
        int v = tid;
        int row = v >> 3, c = (v & 7) ^ (row & 7);
        async_load16(Kp + (size_t)(k0 + row) * HDIM + c * 8, (char*)&Ks[buf][0] + (size_t)v * 16);
        async_load16(Vp + (size_t)row * SEQ + k0 + c * 8, (char*)&Vs[buf][0] + (size_t)v * 16);
    };

    stage(bt0, 0);
    int cb = 0;
    for (int kt = bt0; kt <= bt1; kt++) {
        __syncthreads();
        if (kt < bt1) stage(kt + 1, cb ^ 1);
        const int dt = kt - wqt;
        if (dt >= -4 && dt <= 4) {
            const int k0 = kt * 64;
            f32x4 st[4];
#pragma unroll
            for (int c = 0; c < 4; c++) {
                int row = c * 16 + l15;
                bf16x8 kb0 = *(const bf16x8*)&Ks[cb][row * 64 + (quad ^ (row & 7)) * 8];
                bf16x8 kb1 = *(const bf16x8*)&Ks[cb][row * 64 + ((quad + 4) ^ (row & 7)) * 8];
                f32x4 a = {};
                a = __builtin_amdgcn_mfma_f32_16x16x32_bf16(kb0, qa0, a, 0, 0, 0);  // S^T
                a = __builtin_amdgcn_mfma_f32_16x16x32_bf16(kb1, qa1, a, 0, 0, 0);
                st[c] = a;
            }
            const bool edge = (dt == -4 || dt == 4);
            const int q = qbase + l15;
#pragma unroll
            for (int c = 0; c < 4; c++) {
                bf16x4 pk;
#pragma unroll
                for (int r = 0; r < 4; r++) {
                    float sv = st[c][r];
                    if (edge) {
                        int k = k0 + c * 16 + quad * 4 + r;
                        int dd = q - k; dd = (dd < 0) ? -dd : dd;
                        if (dd > WIN) sv = -1e30f;
                    }
                    pk[r] = (bf16_t)exp2f(sv);
                }
                *(bf16x4*)&Plds[wave][l15][c * 16 + quad * 4] = pk;
            }
            bf16x8 pa0 = *(const bf16x8*)&Plds[wave][l15][quad * 8];
            bf16x8 pa1 = *(const bf16x8*)&Plds[wave][l15][32 + quad * 8];
            lacc = __builtin_amdgcn_mfma_f32_16x16x32_bf16(pa0, ones, lacc, 0, 0, 0);
            lacc = __builtin_amdgcn_mfma_f32_16x16x32_bf16(pa1, ones, lacc, 0, 0, 0);
#pragma unroll
            for (int d = 0; d < 4; d++) {
                int row = d * 16 + l15;
                bf16x8 vb0 = *(const bf16x8*)&Vs[cb][row * 64 + (quad ^ (row & 7)) * 8];
                bf16x8 vb1 = *(const bf16x8*)&Vs[cb][row * 64 + ((quad + 4) ^ (row & 7)) * 8];
                O[d] = __builtin_amdgcn_mfma_f32_16x16x32_bf16(pa0, vb0, O[d], 0, 0, 0);
                O[d] = __builtin_amdgcn_mfma_f32_16x16x32_bf16(pa1, vb1, O[d], 0, 0, 0);
            }
        }
        cb ^= 1;
    }

#pragma unroll
    for (int r = 0; r < 4; r++) {
        float inv = 1.0f / lacc[r];
        int i = qbase + quad * 4 + r;
#pragma unroll
        for (int d = 0; d < 4; d++) {
            float v = O[d][r] * inv;
            ctx[((size_t)(b * SEQ + i)) * DMODEL + h * HDIM + d * 16 + l15] = (bf16_t)v;
        }
    }
}

// ---------------------------------------------------------------------------
extern "C" void kernel_launch(void* const* d_in, const int* in_sizes, int n_in,
                              void* d_out, int out_size, void* d_ws, size_t ws_size,
                              hipStream_t stream) {
    const float* x  = (const float*)d_in[0];
    const float* Wq = (const float*)d_in[1];
    const float* Wk = (const float*)d_in[2];
    const float* Wv = (const float*)d_in[3];
    const float* Wo = (const float*)d_in[4];
    const float* bo = (const float*)d_in[5];
    float* out = (float*)d_out;

    const size_t MTOK = (size_t)BATCH * SEQ;          // 4096
    bf16_t* xb  = (bf16_t*)d_ws;                      // 4096*1024
    bf16_t* Wt  = xb + MTOK * DMODEL;                 // 4*1024*1024
    bf16_t* Qb  = Wt + (size_t)4 * DMODEL * DMODEL;   // [B,H,S,64]
    bf16_t* Kb  = Qb + MTOK * DMODEL;                 // [B,H,S,64]
    bf16_t* Vt  = Kb + MTOK * DMODEL;                 // [B,H,64,S]
    bf16_t* ctx = Vt + MTOK * DMODEL;                 // [4096][1024]
    bf16_t* Vb  = ctx;  // alias: Vb dead before attn writes ctx

    prep_kernel<<<dim3(2048), dim3(256), 0, stream>>>(x, Wq, Wk, Wv, Wo, xb, Wt);
    // QKV: M=4096, N=3072, K=1024; 192 blocks of 512 (256^2 tiles, 4-phase)
    gemm_qkv_kernel<<<dim3(192), dim3(512), 0, stream>>>(xb, Wt, Qb, Kb, Vb);
    vtrans_kernel<<<dim3(32, 32), dim3(64, 4), 0, stream>>>(Vb, Vt);
    attn_kernel<<<dim3(512), dim3(512), 0, stream>>>(Qb, Kb, Vt, ctx);
    // Out: M=4096, N=1024, K=1024; 256 blocks of 256 (128^2, 2-phase dbuf)
    gemm_out_kernel<<<dim3(256), dim3(256), 0, stream>>>(
        ctx, Wt + (size_t)3 * DMODEL * DMODEL, out, bo);
}

// Round 5
// 159.353 us; speedup vs baseline: 1.0981x; 1.0519x over previous
//
#include <hip/hip_runtime.h>
#include <hip/hip_bf16.h>

typedef __bf16 bf16_t;
typedef __bf16 bf16x8 __attribute__((ext_vector_type(8)));
typedef __bf16 bf16x4 __attribute__((ext_vector_type(4)));
typedef float  f32x4  __attribute__((ext_vector_type(4)));

#define SEQ    2048
#define BATCH  2
#define NHEAD  16
#define HDIM   64
#define DMODEL 1024
#define WIN    256

// async global->LDS, 16B per lane (dest = wave-uniform base + lane*16).
__device__ __forceinline__ void async_load16(const void* g, void* l) {
    __builtin_amdgcn_global_load_lds(
        (const __attribute__((address_space(1))) char*)(uintptr_t)g,
        (__attribute__((address_space(3))) char*)(uintptr_t)l, 16, 0, 0);
}

// ---------------------------------------------------------------------------
// Prep kernel: blocks 0..1023 transpose+cast the 4 weight mats (64x64 tiles,
// float4 reads); blocks 1024..2047 cast x -> bf16 (float4).
// ---------------------------------------------------------------------------
__global__ __launch_bounds__(256) void prep_kernel(
    const float* __restrict__ x, const float* __restrict__ Wq,
    const float* __restrict__ Wk, const float* __restrict__ Wv,
    const float* __restrict__ Wo, bf16_t* __restrict__ xb,
    bf16_t* __restrict__ Wt) {
    const int bid = blockIdx.x, tid = threadIdx.x;
    if (bid < 1024) {
        __shared__ float t64[64][65];
        const int mat = bid >> 8, tile = bid & 255;
        const int k0 = (tile >> 4) * 64, n0 = (tile & 15) * 64;
        const float* W = (mat == 0) ? Wq : (mat == 1) ? Wk : (mat == 2) ? Wv : Wo;
        bf16_t* out = Wt + (size_t)mat * DMODEL * DMODEL;
        const int r = tid >> 4, c4 = tid & 15;
#pragma unroll
        for (int i = 0; i < 4; i++) {
            int krow = i * 16 + r;
            float4 v = *(const float4*)&W[(size_t)(k0 + krow) * DMODEL + n0 + c4 * 4];
            t64[krow][c4 * 4 + 0] = v.x; t64[krow][c4 * 4 + 1] = v.y;
            t64[krow][c4 * 4 + 2] = v.z; t64[krow][c4 * 4 + 3] = v.w;
        }
        __syncthreads();
#pragma unroll
        for (int j = 0; j < 4; j++) {
            int nrow = j * 16 + r;
            bf16x4 o;
#pragma unroll
            for (int q = 0; q < 4; q++) o[q] = (bf16_t)t64[c4 * 4 + q][nrow];
            *(bf16x4*)&out[(size_t)(n0 + nrow) * DMODEL + k0 + c4 * 4] = o;
        }
    } else {
        const int cb = bid - 1024;
#pragma unroll
        for (int it = 0; it < 4; it++) {
            int i = (cb * 4 + it) * 256 + tid;
            float4 v = ((const float4*)x)[i];
            bf16x4 o;
            o[0] = (bf16_t)v.x; o[1] = (bf16_t)v.y; o[2] = (bf16_t)v.z; o[3] = (bf16_t)v.w;
            ((bf16x4*)xb)[i] = o;
        }
    }
}

// ---------------------------------------------------------------------------
// QKV GEMM: 256x192 tile, BK=64, 8 waves (2M x 4N), 256 blocks (all CUs).
// SAFE 2-phase double-buffer: stage(t+1) issued BEFORE compute(t) so loads
// overlap the ds_read+MFMA phase; the end-of-iter __syncthreads performs the
// vmcnt(0)+barrier drain (compiler-fenced -- no instruction-motion risk).
// Groups: g0..3 = A rows 0-63/64-127/128-191/192-255; g4..6 = B rows
// 0-63/64-127/128-191. LDS = (256+192)*64*2B*2 = 112 KiB, 1 block/CU.
// Epilogue scatters Q(scaled by 1/8*log2e)/K/V into [B,H,S,64].
// ---------------------------------------------------------------------------
__global__ __launch_bounds__(512) void gemm_qkv_kernel(
    const bf16_t* __restrict__ A, const bf16_t* __restrict__ Bt,
    bf16_t* __restrict__ Qb, bf16_t* __restrict__ Kb, bf16_t* __restrict__ Vb) {
    __shared__ __attribute__((aligned(16))) bf16_t smem[2][(256 + 192) * 64];
    const int tid = threadIdx.x;
    const int wave = tid >> 6, lane = tid & 63, quad = lane >> 4, l15 = lane & 15;
    const int wm = wave >> 2, wn = wave & 3;
    const int id = blockIdx.x, xcd = id & 7, tt = id >> 3;
    const int gidx = xcd * 32 + tt;                 // 256 blocks, bijective
    const int m0 = (gidx & 15) * 256, n0 = (gidx >> 4) * 192;

    const int cth = (tid & 7) ^ ((tid >> 3) & 7);   // swizzled source chunk
    const int rA = tid >> 3;                        // row-in-group 0..63

    auto stage = [&](int tile, int buf) {
#pragma unroll
        for (int gr = 0; gr < 4; ++gr)              // A: 256 rows
            async_load16(A + (size_t)(m0 + gr * 64 + rA) * 1024 + tile * 64 + cth * 8,
                         (char*)&smem[buf][0] + (size_t)(gr * 512 + tid) * 16);
#pragma unroll
        for (int gr = 0; gr < 3; ++gr)              // B: 192 rows
            async_load16(Bt + (size_t)(n0 + gr * 64 + rA) * 1024 + tile * 64 + cth * 8,
                         (char*)&smem[buf][256 * 64] + (size_t)(gr * 512 + tid) * 16);
    };

    const int swz  = l15 & 7;
    const int rowA = wm * 128 + l15;
    const int rowB = wn * 48 + l15;                 // 48*wn ≡ 0 mod 8 -> swz ok

    f32x4 acc[8][3] = {};

    stage(0, 0);
    __syncthreads();
    int cur = 0;
#pragma unroll 1
    for (int t = 0; t < 16; ++t) {
        if (t + 1 < 16) stage(t + 1, cur ^ 1);      // loads fly under compute
        const bf16_t* as = &smem[cur][0];
        const bf16_t* bs = &smem[cur][256 * 64];
#pragma unroll
        for (int kk = 0; kk < 2; ++kk) {
            const int chk = ((kk * 4 + quad) ^ swz) * 8;
            bf16x8 am[8], bn[3];
#pragma unroll
            for (int i = 0; i < 8; i++)
                am[i] = *(const bf16x8*)&as[(rowA + i * 16) * 64 + chk];
#pragma unroll
            for (int j = 0; j < 3; j++)
                bn[j] = *(const bf16x8*)&bs[(rowB + j * 16) * 64 + chk];
#pragma unroll
            for (int i = 0; i < 8; i++)
#pragma unroll
                for (int j = 0; j < 3; j++)
                    acc[i][j] = __builtin_amdgcn_mfma_f32_16x16x32_bf16(am[i], bn[j], acc[i][j], 0, 0, 0);
        }
        __syncthreads();                            // vmcnt(0)+barrier drain
        cur ^= 1;
    }

#pragma unroll
    for (int i = 0; i < 8; i++)
#pragma unroll
        for (int j = 0; j < 3; j++)
#pragma unroll
            for (int r = 0; r < 4; r++) {
                int mg = m0 + wm * 128 + i * 16 + quad * 4 + r;
                int ng = n0 + wn * 48 + j * 16 + l15;
                float v = acc[i][j][r];
                int sel = ng >> 10, nl = ng & 1023, h = nl >> 6, d = nl & 63;
                int b = mg >> 11, s = mg & 2047;
                size_t idx = ((size_t)((b * NHEAD + h) * SEQ) + s) * HDIM + d;
                if (sel == 0)      Qb[idx] = (bf16_t)(v * 0.18033688011112042f);
                else if (sel == 1) Kb[idx] = (bf16_t)v;
                else               Vb[idx] = (bf16_t)v;
            }
}

// ---------------------------------------------------------------------------
// Out GEMM: 64x128 tile, 512 blocks (2+ blocks/CU; 48 KiB LDS) -- the
// __syncthreads drain is hidden by the co-resident block. Proven 2-phase
// dbuf structure.
// ---------------------------------------------------------------------------
__global__ __launch_bounds__(256) void gemm_out_kernel(
    const bf16_t* __restrict__ A, const bf16_t* __restrict__ Bt,
    float* __restrict__ Out, const float* __restrict__ bo) {
    __shared__ __attribute__((aligned(16))) bf16_t As[2][64 * 64];
    __shared__ __attribute__((aligned(16))) bf16_t Bs[2][128 * 64];
    const int tid = threadIdx.x;
    const int wn = tid >> 6, lane = tid & 63, quad = lane >> 4, l15 = lane & 15;
    const int id = blockIdx.x, xcd = id & 7, mt = id >> 3;
    const int m0 = mt * 64, n0 = xcd * 128;        // M=4096(64x64) x N=1024(8x128)

    auto stage = [&](int kt, int buf) {
#pragma unroll
        for (int i = 0; i < 2; i++) {
            int v = tid + i * 256;
            int row = v >> 3, c = (v & 7) ^ (row & 7);
            async_load16(A + (size_t)(m0 + row) * 1024 + kt * 64 + c * 8,
                         (char*)&As[buf][0] + (size_t)v * 16);
        }
#pragma unroll
        for (int i = 0; i < 4; i++) {
            int v = tid + i * 256;
            int row = v >> 3, c = (v & 7) ^ (row & 7);
            async_load16(Bt + (size_t)(n0 + row) * 1024 + kt * 64 + c * 8,
                         (char*)&Bs[buf][0] + (size_t)v * 16);
        }
    };

    f32x4 acc[4][2] = {};
    stage(0, 0);
    __syncthreads();
    int cur = 0;
    for (int kt = 0; kt < 16; ++kt) {
        if (kt + 1 < 16) stage(kt + 1, cur ^ 1);
#pragma unroll
        for (int kk = 0; kk < 64; kk += 32) {
            bf16x8 am[4], bn[2];
#pragma unroll
            for (int i = 0; i < 4; i++) {
                int row = i * 16 + l15;
                int ch = ((kk >> 3) + quad) ^ (row & 7);
                am[i] = *(const bf16x8*)&As[cur][row * 64 + ch * 8];
            }
#pragma unroll
            for (int j = 0; j < 2; j++) {
                int row = wn * 32 + j * 16 + l15;
                int ch = ((kk >> 3) + quad) ^ (row & 7);
                bn[j] = *(const bf16x8*)&Bs[cur][row * 64 + ch * 8];
            }
#pragma unroll
            for (int i = 0; i < 4; i++)
#pragma unroll
                for (int j = 0; j < 2; j++)
                    acc[i][j] = __builtin_amdgcn_mfma_f32_16x16x32_bf16(am[i], bn[j], acc[i][j], 0, 0, 0);
        }
        __syncthreads();                           // vmcnt(0)+barrier drain
        cur ^= 1;
    }

#pragma unroll
    for (int i = 0; i < 4; i++)
#pragma unroll
        for (int j = 0; j < 2; j++)
#pragma unroll
            for (int r = 0; r < 4; r++) {
                int mg = m0 + i * 16 + quad * 4 + r;
                int ng = n0 + wn * 32 + j * 16 + l15;
                Out[(size_t)mg * DMODEL + ng] = acc[i][j][r] + bo[ng];
            }
}

// ---------------------------------------------------------------------------
// Kernel: V transpose, Vb[B,H,S,64] -> Vt[B,H,64,S]. Block (64,4), 64x64 tile.
// ---------------------------------------------------------------------------
__global__ __launch_bounds__(256) void vtrans_kernel(const bf16_t* __restrict__ Vb,
                                                     bf16_t* __restrict__ Vt) {
    __shared__ bf16_t tile[64][65];
    const int bh = blockIdx.y, s0 = blockIdx.x * 64;
    const int tx = threadIdx.x, ty = threadIdx.y;
    const bf16_t* src = Vb + ((size_t)bh * SEQ + s0) * HDIM;
    bf16_t* dst = Vt + (size_t)bh * HDIM * SEQ + s0;
#pragma unroll
    for (int i = 0; i < 16; i++) {
        int row = i * 4 + ty;
        tile[row][tx] = src[(size_t)row * HDIM + tx];
    }
    __syncthreads();
#pragma unroll
    for (int i = 0; i < 16; i++) {
        int d = i * 4 + ty;
        dst[(size_t)d * SEQ + tx] = tile[tx][d];
    }
}

// ---------------------------------------------------------------------------
// Attention v5 (proven): swapped QK^T, exp2, 1 __syncthreads per tile.
// ---------------------------------------------------------------------------
__global__ __launch_bounds__(512) void attn_kernel(
    const bf16_t* __restrict__ Qb, const bf16_t* __restrict__ Kb,
    const bf16_t* __restrict__ Vt, bf16_t* __restrict__ ctx) {
    __shared__ __attribute__((aligned(16))) bf16_t Ks[2][64 * 64];
    __shared__ __attribute__((aligned(16))) bf16_t Vs[2][64 * 64];
    __shared__ __attribute__((aligned(16))) bf16_t Plds[8][16][72];
    const int tid = threadIdx.x;
    const int wave = tid >> 6, lane = tid & 63, quad = lane >> 4, l15 = lane & 15;

    const int id = blockIdx.x;
    const int task = (id & 7) * 64 + (id >> 3);
    const int b = task >> 8, h = (task >> 4) & 15, Q0 = (task & 15) << 7;
    const int qbase = Q0 + wave * 16;
    const int wqt = (Q0 >> 6) + (wave >> 2);

    const bf16_t* Qp = Qb + (size_t)(b * NHEAD + h) * SEQ * HDIM;
    const bf16_t* Kp = Kb + (size_t)(b * NHEAD + h) * SEQ * HDIM;
    const bf16_t* Vp = Vt + (size_t)(b * NHEAD + h) * HDIM * SEQ;

    bf16x8 qa0 = *(const bf16x8*)(Qp + (size_t)(qbase + l15) * HDIM + quad * 8);
    bf16x8 qa1 = *(const bf16x8*)(Qp + (size_t)(qbase + l15) * HDIM + 32 + quad * 8);

    bf16x8 ones;
#pragma unroll
    for (int j = 0; j < 8; j++) ones[j] = (bf16_t)1.0f;

    f32x4 O[4] = {};
    f32x4 lacc = {};

    const int base_t = Q0 >> 6;
    const int bt0 = (base_t - 4 > 0) ? base_t - 4 : 0;
    const int bt1 = (base_t + 5 < SEQ / 64 - 1) ? base_t + 5 : SEQ / 64 - 1;

    auto stage = [&](int kt, int buf) {
        const int k0 = kt * 64;
        int v = tid;
        int row = v >> 3, c = (v & 7) ^ (row & 7);
        async_load16(Kp + (size_t)(k0 + row) * HDIM + c * 8, (char*)&Ks[buf][0] + (size_t)v * 16);
        async_load16(Vp + (size_t)row * SEQ + k0 + c * 8, (char*)&Vs[buf][0] + (size_t)v * 16);
    };

    stage(bt0, 0);
    int cb = 0;
    for (int kt = bt0; kt <= bt1; kt++) {
        __syncthreads();
        if (kt < bt1) stage(kt + 1, cb ^ 1);
        const int dt = kt - wqt;
        if (dt >= -4 && dt <= 4) {
            const int k0 = kt * 64;
            f32x4 st[4];
#pragma unroll
            for (int c = 0; c < 4; c++) {
                int row = c * 16 + l15;
                bf16x8 kb0 = *(const bf16x8*)&Ks[cb][row * 64 + (quad ^ (row & 7)) * 8];
                bf16x8 kb1 = *(const bf16x8*)&Ks[cb][row * 64 + ((quad + 4) ^ (row & 7)) * 8];
                f32x4 a = {};
                a = __builtin_amdgcn_mfma_f32_16x16x32_bf16(kb0, qa0, a, 0, 0, 0);  // S^T
                a = __builtin_amdgcn_mfma_f32_16x16x32_bf16(kb1, qa1, a, 0, 0, 0);
                st[c] = a;
            }
            const bool edge = (dt == -4 || dt == 4);
            const int q = qbase + l15;
#pragma unroll
            for (int c = 0; c < 4; c++) {
                bf16x4 pk;
#pragma unroll
                for (int r = 0; r < 4; r++) {
                    float sv = st[c][r];
                    if (edge) {
                        int k = k0 + c * 16 + quad * 4 + r;
                        int dd = q - k; dd = (dd < 0) ? -dd : dd;
                        if (dd > WIN) sv = -1e30f;
                    }
                    pk[r] = (bf16_t)exp2f(sv);
                }
                *(bf16x4*)&Plds[wave][l15][c * 16 + quad * 4] = pk;
            }
            bf16x8 pa0 = *(const bf16x8*)&Plds[wave][l15][quad * 8];
            bf16x8 pa1 = *(const bf16x8*)&Plds[wave][l15][32 + quad * 8];
            lacc = __builtin_amdgcn_mfma_f32_16x16x32_bf16(pa0, ones, lacc, 0, 0, 0);
            lacc = __builtin_amdgcn_mfma_f32_16x16x32_bf16(pa1, ones, lacc, 0, 0, 0);
#pragma unroll
            for (int d = 0; d < 4; d++) {
                int row = d * 16 + l15;
                bf16x8 vb0 = *(const bf16x8*)&Vs[cb][row * 64 + (quad ^ (row & 7)) * 8];
                bf16x8 vb1 = *(const bf16x8*)&Vs[cb][row * 64 + ((quad + 4) ^ (row & 7)) * 8];
                O[d] = __builtin_amdgcn_mfma_f32_16x16x32_bf16(pa0, vb0, O[d], 0, 0, 0);
                O[d] = __builtin_amdgcn_mfma_f32_16x16x32_bf16(pa1, vb1, O[d], 0, 0, 0);
            }
        }
        cb ^= 1;
    }

#pragma unroll
    for (int r = 0; r < 4; r++) {
        float inv = 1.0f / lacc[r];
        int i = qbase + quad * 4 + r;
#pragma unroll
        for (int d = 0; d < 4; d++) {
            float v = O[d][r] * inv;
            ctx[((size_t)(b * SEQ + i)) * DMODEL + h * HDIM + d * 16 + l15] = (bf16_t)v;
        }
    }
}

// ---------------------------------------------------------------------------
extern "C" void kernel_launch(void* const* d_in, const int* in_sizes, int n_in,
                              void* d_out, int out_size, void* d_ws, size_t ws_size,
                              hipStream_t stream) {
    const float* x  = (const float*)d_in[0];
    const float* Wq = (const float*)d_in[1];
    const float* Wk = (const float*)d_in[2];
    const float* Wv = (const float*)d_in[3];
    const float* Wo = (const float*)d_in[4];
    const float* bo = (const float*)d_in[5];
    float* out = (float*)d_out;

    const size_t MTOK = (size_t)BATCH * SEQ;          // 4096
    bf16_t* xb  = (bf16_t*)d_ws;                      // 4096*1024
    bf16_t* Wt  = xb + MTOK * DMODEL;                 // 4*1024*1024
    bf16_t* Qb  = Wt + (size_t)4 * DMODEL * DMODEL;   // [B,H,S,64]
    bf16_t* Kb  = Qb + MTOK * DMODEL;                 // [B,H,S,64]
    bf16_t* Vt  = Kb + MTOK * DMODEL;                 // [B,H,64,S]
    bf16_t* ctx = Vt + MTOK * DMODEL;                 // [4096][1024]
    bf16_t* Vb  = ctx;  // alias: Vb dead before attn writes ctx

    prep_kernel<<<dim3(2048), dim3(256), 0, stream>>>(x, Wq, Wk, Wv, Wo, xb, Wt);
    // QKV: M=4096, N=3072, K=1024; 256 blocks of 512 (256x192 tiles, 2-phase)
    gemm_qkv_kernel<<<dim3(256), dim3(512), 0, stream>>>(xb, Wt, Qb, Kb, Vb);
    vtrans_kernel<<<dim3(32, 32), dim3(64, 4), 0, stream>>>(Vb, Vt);
    attn_kernel<<<dim3(512), dim3(512), 0, stream>>>(Qb, Kb, Vt, ctx);
    // Out: M=4096, N=1024, K=1024; 512 blocks of 256 (64x128, 2-phase dbuf)
    gemm_out_kernel<<<dim3(512), dim3(256), 0, stream>>>(
        ctx, Wt + (size_t)3 * DMODEL * DMODEL, out, bo);
}

// Round 6
// 157.605 us; speedup vs baseline: 1.1102x; 1.0111x over previous
//
#include <hip/hip_runtime.h>
#include <hip/hip_bf16.h>

typedef __bf16 bf16_t;
typedef __bf16 bf16x8 __attribute__((ext_vector_type(8)));
typedef __bf16 bf16x4 __attribute__((ext_vector_type(4)));
typedef float  f32x4  __attribute__((ext_vector_type(4)));

#define SEQ    2048
#define BATCH  2
#define NHEAD  16
#define HDIM   64
#define DMODEL 1024
#define WIN    256

// async global->LDS, 16B per lane (dest = wave-uniform base + lane*16).
__device__ __forceinline__ void async_load16(const void* g, void* l) {
    __builtin_amdgcn_global_load_lds(
        (const __attribute__((address_space(1))) char*)(uintptr_t)g,
        (__attribute__((address_space(3))) char*)(uintptr_t)l, 16, 0, 0);
}

// ---------------------------------------------------------------------------
// Prep kernel: blocks 0..1023 transpose+cast the 4 weight mats (64x64 tiles,
// float4 reads); blocks 1024..2047 cast x -> bf16 (float4).
// ---------------------------------------------------------------------------
__global__ __launch_bounds__(256) void prep_kernel(
    const float* __restrict__ x, const float* __restrict__ Wq,
    const float* __restrict__ Wk, const float* __restrict__ Wv,
    const float* __restrict__ Wo, bf16_t* __restrict__ xb,
    bf16_t* __restrict__ Wt) {
    const int bid = blockIdx.x, tid = threadIdx.x;
    if (bid < 1024) {
        __shared__ float t64[64][65];
        const int mat = bid >> 8, tile = bid & 255;
        const int k0 = (tile >> 4) * 64, n0 = (tile & 15) * 64;
        const float* W = (mat == 0) ? Wq : (mat == 1) ? Wk : (mat == 2) ? Wv : Wo;
        bf16_t* out = Wt + (size_t)mat * DMODEL * DMODEL;
        const int r = tid >> 4, c4 = tid & 15;
#pragma unroll
        for (int i = 0; i < 4; i++) {
            int krow = i * 16 + r;
            float4 v = *(const float4*)&W[(size_t)(k0 + krow) * DMODEL + n0 + c4 * 4];
            t64[krow][c4 * 4 + 0] = v.x; t64[krow][c4 * 4 + 1] = v.y;
            t64[krow][c4 * 4 + 2] = v.z; t64[krow][c4 * 4 + 3] = v.w;
        }
        __syncthreads();
#pragma unroll
        for (int j = 0; j < 4; j++) {
            int nrow = j * 16 + r;
            bf16x4 o;
#pragma unroll
            for (int q = 0; q < 4; q++) o[q] = (bf16_t)t64[c4 * 4 + q][nrow];
            *(bf16x4*)&out[(size_t)(n0 + nrow) * DMODEL + k0 + c4 * 4] = o;
        }
    } else {
        const int cb = bid - 1024;
#pragma unroll
        for (int it = 0; it < 4; it++) {
            int i = (cb * 4 + it) * 256 + tid;
            float4 v = ((const float4*)x)[i];
            bf16x4 o;
            o[0] = (bf16_t)v.x; o[1] = (bf16_t)v.y; o[2] = (bf16_t)v.z; o[3] = (bf16_t)v.w;
            ((bf16x4*)xb)[i] = o;
        }
    }
}

// ---------------------------------------------------------------------------
// QKV GEMM: 256x192 tile, BK=64, 8 waves (2M x 4N), 256 blocks (all CUs),
// safe 2-phase double-buffer (stage t+1 before compute t; __syncthreads
// drain). Epilogue: Q scaled by 1/8*log2e -> Qb[B,H,S,64]; K -> Kb[B,H,S,64];
// V written DIRECTLY TRANSPOSED -> Vt[B,H,64,S] (bf16x4 over 4 consecutive s
// per lane; a wave covers 32B runs per d and the i-loop completes 64B lines,
// so L2 write-combining keeps HBM write at 8MB). Kills the vtrans kernel.
// ---------------------------------------------------------------------------
__global__ __launch_bounds__(512) void gemm_qkv_kernel(
    const bf16_t* __restrict__ A, const bf16_t* __restrict__ Bt,
    bf16_t* __restrict__ Qb, bf16_t* __restrict__ Kb, bf16_t* __restrict__ Vt) {
    __shared__ __attribute__((aligned(16))) bf16_t smem[2][(256 + 192) * 64];
    const int tid = threadIdx.x;
    const int wave = tid >> 6, lane = tid & 63, quad = lane >> 4, l15 = lane & 15;
    const int wm = wave >> 2, wn = wave & 3;
    const int id = blockIdx.x, xcd = id & 7, tt = id >> 3;
    const int gidx = xcd * 32 + tt;                 // 256 blocks, bijective
    const int m0 = (gidx & 15) * 256, n0 = (gidx >> 4) * 192;

    const int cth = (tid & 7) ^ ((tid >> 3) & 7);   // swizzled source chunk
    const int rA = tid >> 3;                        // row-in-group 0..63

    auto stage = [&](int tile, int buf) {
#pragma unroll
        for (int gr = 0; gr < 4; ++gr)              // A: 256 rows
            async_load16(A + (size_t)(m0 + gr * 64 + rA) * 1024 + tile * 64 + cth * 8,
                         (char*)&smem[buf][0] + (size_t)(gr * 512 + tid) * 16);
#pragma unroll
        for (int gr = 0; gr < 3; ++gr)              // B: 192 rows
            async_load16(Bt + (size_t)(n0 + gr * 64 + rA) * 1024 + tile * 64 + cth * 8,
                         (char*)&smem[buf][256 * 64] + (size_t)(gr * 512 + tid) * 16);
    };

    const int swz  = l15 & 7;
    const int rowA = wm * 128 + l15;
    const int rowB = wn * 48 + l15;                 // 48*wn ≡ 0 mod 8 -> swz ok

    f32x4 acc[8][3] = {};

    stage(0, 0);
    __syncthreads();
    int cur = 0;
#pragma unroll 1
    for (int t = 0; t < 16; ++t) {
        if (t + 1 < 16) stage(t + 1, cur ^ 1);      // loads fly under compute
        const bf16_t* as = &smem[cur][0];
        const bf16_t* bs = &smem[cur][256 * 64];
#pragma unroll
        for (int kk = 0; kk < 2; ++kk) {
            const int chk = ((kk * 4 + quad) ^ swz) * 8;
            bf16x8 am[8], bn[3];
#pragma unroll
            for (int i = 0; i < 8; i++)
                am[i] = *(const bf16x8*)&as[(rowA + i * 16) * 64 + chk];
#pragma unroll
            for (int j = 0; j < 3; j++)
                bn[j] = *(const bf16x8*)&bs[(rowB + j * 16) * 64 + chk];
#pragma unroll
            for (int i = 0; i < 8; i++)
#pragma unroll
                for (int j = 0; j < 3; j++)
                    acc[i][j] = __builtin_amdgcn_mfma_f32_16x16x32_bf16(am[i], bn[j], acc[i][j], 0, 0, 0);
        }
        __syncthreads();                            // vmcnt(0)+barrier drain
        cur ^= 1;
    }

#pragma unroll
    for (int i = 0; i < 8; i++)
#pragma unroll
        for (int j = 0; j < 3; j++) {
            const int mg0 = m0 + wm * 128 + i * 16 + quad * 4;   // r=0, 4-aligned
            const int ng  = n0 + wn * 48 + j * 16 + l15;
            const int sel = ng >> 10, nl = ng & 1023, h = nl >> 6, d = nl & 63;
            const int b = mg0 >> 11, s0 = mg0 & 2047;            // const over r
            if (sel == 2) {
                // V transposed: Vt[((b*16+h)*64+d)*2048 + s0 .. +3]
                bf16x4 o;
#pragma unroll
                for (int r = 0; r < 4; r++) o[r] = (bf16_t)acc[i][j][r];
                *(bf16x4*)&Vt[((size_t)((b * NHEAD + h) * HDIM + d)) * SEQ + s0] = o;
            } else {
#pragma unroll
                for (int r = 0; r < 4; r++) {
                    float v = acc[i][j][r];
                    size_t idx = ((size_t)((b * NHEAD + h) * SEQ) + s0 + r) * HDIM + d;
                    if (sel == 0) Qb[idx] = (bf16_t)(v * 0.18033688011112042f);
                    else          Kb[idx] = (bf16_t)v;
                }
            }
        }
}

// ---------------------------------------------------------------------------
// Out GEMM: 64x128 tile, 512 blocks (2+ blocks/CU; 48 KiB LDS) -- the
// __syncthreads drain is hidden by the co-resident block. Proven 2-phase
// dbuf structure.
// ---------------------------------------------------------------------------
__global__ __launch_bounds__(256) void gemm_out_kernel(
    const bf16_t* __restrict__ A, const bf16_t* __restrict__ Bt,
    float* __restrict__ Out, const float* __restrict__ bo) {
    __shared__ __attribute__((aligned(16))) bf16_t As[2][64 * 64];
    __shared__ __attribute__((aligned(16))) bf16_t Bs[2][128 * 64];
    const int tid = threadIdx.x;
    const int wn = tid >> 6, lane = tid & 63, quad = lane >> 4, l15 = lane & 15;
    const int id = blockIdx.x, xcd = id & 7, mt = id >> 3;
    const int m0 = mt * 64, n0 = xcd * 128;        // M=4096(64x64) x N=1024(8x128)

    auto stage = [&](int kt, int buf) {
#pragma unroll
        for (int i = 0; i < 2; i++) {
            int v = tid + i * 256;
            int row = v >> 3, c = (v & 7) ^ (row & 7);
            async_load16(A + (size_t)(m0 + row) * 1024 + kt * 64 + c * 8,
                         (char*)&As[buf][0] + (size_t)v * 16);
        }
#pragma unroll
        for (int i = 0; i < 4; i++) {
            int v = tid + i * 256;
            int row = v >> 3, c = (v & 7) ^ (row & 7);
            async_load16(Bt + (size_t)(n0 + row) * 1024 + kt * 64 + c * 8,
                         (char*)&Bs[buf][0] + (size_t)v * 16);
        }
    };

    f32x4 acc[4][2] = {};
    stage(0, 0);
    __syncthreads();
    int cur = 0;
    for (int kt = 0; kt < 16; ++kt) {
        if (kt + 1 < 16) stage(kt + 1, cur ^ 1);
#pragma unroll
        for (int kk = 0; kk < 64; kk += 32) {
            bf16x8 am[4], bn[2];
#pragma unroll
            for (int i = 0; i < 4; i++) {
                int row = i * 16 + l15;
                int ch = ((kk >> 3) + quad) ^ (row & 7);
                am[i] = *(const bf16x8*)&As[cur][row * 64 + ch * 8];
            }
#pragma unroll
            for (int j = 0; j < 2; j++) {
                int row = wn * 32 + j * 16 + l15;
                int ch = ((kk >> 3) + quad) ^ (row & 7);
                bn[j] = *(const bf16x8*)&Bs[cur][row * 64 + ch * 8];
            }
#pragma unroll
            for (int i = 0; i < 4; i++)
#pragma unroll
                for (int j = 0; j < 2; j++)
                    acc[i][j] = __builtin_amdgcn_mfma_f32_16x16x32_bf16(am[i], bn[j], acc[i][j], 0, 0, 0);
        }
        __syncthreads();                           // vmcnt(0)+barrier drain
        cur ^= 1;
    }

#pragma unroll
    for (int i = 0; i < 4; i++)
#pragma unroll
        for (int j = 0; j < 2; j++)
#pragma unroll
            for (int r = 0; r < 4; r++) {
                int mg = m0 + i * 16 + quad * 4 + r;
                int ng = n0 + wn * 32 + j * 16 + l15;
                Out[(size_t)mg * DMODEL + ng] = acc[i][j][r] + bo[ng];
            }
}

// ---------------------------------------------------------------------------
// Attention v6: swapped QK^T, exp2, 1 __syncthreads per tile. Row-sum now
// done in-register (each lane holds 16 P values/tile in the S^T layout;
// accumulate bf16-rounded values in fp32 = same numerics as the old
// ones-MFMA), cross-quad reduce via 2 shfl_xor at the end; denominator
// transposed into the O layout with 4 shfl. Drops 2 MFMA/tile + ones/lacc.
// ---------------------------------------------------------------------------
__global__ __launch_bounds__(512) void attn_kernel(
    const bf16_t* __restrict__ Qb, const bf16_t* __restrict__ Kb,
    const bf16_t* __restrict__ Vt, bf16_t* __restrict__ ctx) {
    __shared__ __attribute__((aligned(16))) bf16_t Ks[2][64 * 64];
    __shared__ __attribute__((aligned(16))) bf16_t Vs[2][64 * 64];
    __shared__ __attribute__((aligned(16))) bf16_t Plds[8][16][72];
    const int tid = threadIdx.x;
    const int wave = tid >> 6, lane = tid & 63, quad = lane >> 4, l15 = lane & 15;

    const int id = blockIdx.x;
    const int task = (id & 7) * 64 + (id >> 3);
    const int b = task >> 8, h = (task >> 4) & 15, Q0 = (task & 15) << 7;
    const int qbase = Q0 + wave * 16;
    const int wqt = (Q0 >> 6) + (wave >> 2);

    const bf16_t* Qp = Qb + (size_t)(b * NHEAD + h) * SEQ * HDIM;
    const bf16_t* Kp = Kb + (size_t)(b * NHEAD + h) * SEQ * HDIM;
    const bf16_t* Vp = Vt + (size_t)(b * NHEAD + h) * HDIM * SEQ;

    bf16x8 qa0 = *(const bf16x8*)(Qp + (size_t)(qbase + l15) * HDIM + quad * 8);
    bf16x8 qa1 = *(const bf16x8*)(Qp + (size_t)(qbase + l15) * HDIM + 32 + quad * 8);

    f32x4 O[4] = {};
    float psum = 0.0f;

    const int base_t = Q0 >> 6;
    const int bt0 = (base_t - 4 > 0) ? base_t - 4 : 0;
    const int bt1 = (base_t + 5 < SEQ / 64 - 1) ? base_t + 5 : SEQ / 64 - 1;

    auto stage = [&](int kt, int buf) {
        const int k0 = kt * 64;
        int v = tid;
        int row = v >> 3, c = (v & 7) ^ (row & 7);
        async_load16(Kp + (size_t)(k0 + row) * HDIM + c * 8, (char*)&Ks[buf][0] + (size_t)v * 16);
        async_load16(Vp + (size_t)row * SEQ + k0 + c * 8, (char*)&Vs[buf][0] + (size_t)v * 16);
    };

    stage(bt0, 0);
    int cb = 0;
    for (int kt = bt0; kt <= bt1; kt++) {
        __syncthreads();
        if (kt < bt1) stage(kt + 1, cb ^ 1);
        const int dt = kt - wqt;
        if (dt >= -4 && dt <= 4) {
            const int k0 = kt * 64;
            f32x4 st[4];
#pragma unroll
            for (int c = 0; c < 4; c++) {
                int row = c * 16 + l15;
                bf16x8 kb0 = *(const bf16x8*)&Ks[cb][row * 64 + (quad ^ (row & 7)) * 8];
                bf16x8 kb1 = *(const bf16x8*)&Ks[cb][row * 64 + ((quad + 4) ^ (row & 7)) * 8];
                f32x4 a = {};
                a = __builtin_amdgcn_mfma_f32_16x16x32_bf16(kb0, qa0, a, 0, 0, 0);  // S^T
                a = __builtin_amdgcn_mfma_f32_16x16x32_bf16(kb1, qa1, a, 0, 0, 0);
                st[c] = a;
            }
            const bool edge = (dt == -4 || dt == 4);
            const int q = qbase + l15;
#pragma unroll
            for (int c = 0; c < 4; c++) {
                bf16x4 pk;
#pragma unroll
                for (int r = 0; r < 4; r++) {
                    float sv = st[c][r];
                    if (edge) {
                        int k = k0 + c * 16 + quad * 4 + r;
                        int dd = q - k; dd = (dd < 0) ? -dd : dd;
                        if (dd > WIN) sv = -1e30f;
                    }
                    pk[r] = (bf16_t)exp2f(sv);
                    psum += (float)pk[r];          // bf16-rounded, fp32 accum
                }
                *(bf16x4*)&Plds[wave][l15][c * 16 + quad * 4] = pk;
            }
            bf16x8 pa0 = *(const bf16x8*)&Plds[wave][l15][quad * 8];
            bf16x8 pa1 = *(const bf16x8*)&Plds[wave][l15][32 + quad * 8];
#pragma unroll
            for (int d = 0; d < 4; d++) {
                int row = d * 16 + l15;
                bf16x8 vb0 = *(const bf16x8*)&Vs[cb][row * 64 + (quad ^ (row & 7)) * 8];
                bf16x8 vb1 = *(const bf16x8*)&Vs[cb][row * 64 + ((quad + 4) ^ (row & 7)) * 8];
                O[d] = __builtin_amdgcn_mfma_f32_16x16x32_bf16(pa0, vb0, O[d], 0, 0, 0);
                O[d] = __builtin_amdgcn_mfma_f32_16x16x32_bf16(pa1, vb1, O[d], 0, 0, 0);
            }
        }
        cb ^= 1;
    }

    // cross-quad reduce: every lane ends with full row-sum for q = qbase+l15
    psum += __shfl_xor(psum, 16, 64);
    psum += __shfl_xor(psum, 32, 64);

#pragma unroll
    for (int r = 0; r < 4; r++) {
        // O's row q = qbase + quad*4 + r lives at source lane l15' = quad*4+r
        float s_q = __shfl(psum, (quad << 4) | (quad * 4 + r), 64);
        float inv = 1.0f / s_q;
        int i = qbase + quad * 4 + r;
#pragma unroll
        for (int d = 0; d < 4; d++) {
            float v = O[d][r] * inv;
            ctx[((size_t)(b * SEQ + i)) * DMODEL + h * HDIM + d * 16 + l15] = (bf16_t)v;
        }
    }
}

// ---------------------------------------------------------------------------
extern "C" void kernel_launch(void* const* d_in, const int* in_sizes, int n_in,
                              void* d_out, int out_size, void* d_ws, size_t ws_size,
                              hipStream_t stream) {
    const float* x  = (const float*)d_in[0];
    const float* Wq = (const float*)d_in[1];
    const float* Wk = (const float*)d_in[2];
    const float* Wv = (const float*)d_in[3];
    const float* Wo = (const float*)d_in[4];
    const float* bo = (const float*)d_in[5];
    float* out = (float*)d_out;

    const size_t MTOK = (size_t)BATCH * SEQ;          // 4096
    bf16_t* xb  = (bf16_t*)d_ws;                      // 4096*1024
    bf16_t* Wt  = xb + MTOK * DMODEL;                 // 4*1024*1024
    bf16_t* Qb  = Wt + (size_t)4 * DMODEL * DMODEL;   // [B,H,S,64]
    bf16_t* Kb  = Qb + MTOK * DMODEL;                 // [B,H,S,64]
    bf16_t* Vt  = Kb + MTOK * DMODEL;                 // [B,H,64,S] (written by QKV)
    bf16_t* ctx = Vt + MTOK * DMODEL;                 // [4096][1024]

    prep_kernel<<<dim3(2048), dim3(256), 0, stream>>>(x, Wq, Wk, Wv, Wo, xb, Wt);
    // QKV: M=4096, N=3072, K=1024; 256 blocks of 512 (256x192 tiles, 2-phase)
    gemm_qkv_kernel<<<dim3(256), dim3(512), 0, stream>>>(xb, Wt, Qb, Kb, Vt);
    attn_kernel<<<dim3(512), dim3(512), 0, stream>>>(Qb, Kb, Vt, ctx);
    // Out: M=4096, N=1024, K=1024; 512 blocks of 256 (64x128, 2-phase dbuf)
    gemm_out_kernel<<<dim3(512), dim3(256), 0, stream>>>(
        ctx, Wt + (size_t)3 * DMODEL * DMODEL, out, bo);
}